// Round 8
// baseline (263.188 us; speedup 1.0000x reference)
//
#include <hip/hip_runtime.h>
#include <hip/hip_bf16.h>

#define NB 512
#define CIN 32
#define LEN 512
#define NE 8
#define NPOOL 16
#define DIN 16384
#define DOUT 768
#define HD 1024
#define F1 128

#define MT 256      // GEMM M tile (covers whole expert)
#define NT 64       // GEMM N tile (12 n-tiles over DOUT=768)
#define BK 32       // K step

typedef __attribute__((ext_vector_type(4))) float f32x4;
typedef __attribute__((ext_vector_type(8))) short s16x8;
typedef __attribute__((ext_vector_type(4))) unsigned int u32x4;

__device__ __forceinline__ float gelu_erf(float v) {
    return 0.5f * v * (1.0f + erff(v * 0.70710678118654752f));
}

__device__ __forceinline__ unsigned cvt_pk(float lo, float hi) {
    unsigned r;
    asm volatile("v_cvt_pk_bf16_f32 %0, %1, %2" : "=v"(r) : "v"(lo), "v"(hi));
    return r;
}

__device__ __forceinline__ unsigned short f2bf_u(float f) {
    union { float f; unsigned u; } x; x.f = f;
    unsigned r = x.u + 0x7fffu + ((x.u >> 16) & 1u);
    return (unsigned short)(r >> 16);
}

// async global->LDS DMA, 16B/lane, LDS dest = wave-uniform base + lane*16
__device__ __forceinline__ void gload_lds16(const void* gptr, void* lptr) {
    __builtin_amdgcn_global_load_lds(
        (const __attribute__((address_space(1))) unsigned int*)gptr,
        (__attribute__((address_space(3))) unsigned int*)lptr,
        16, 0, 0);
}

// ---------------- Kernel 0: x fp32 -> bf16 (one-time, feeds GEMM A-path) ------------------
__global__ __launch_bounds__(256) void kcvt(const float* __restrict__ x,
                                            unsigned short* __restrict__ xb)
{
    int i = blockIdx.x * 256 + threadIdx.x;          // 1M threads x 8 floats
    const f32x4* src = (const f32x4*)(x + (size_t)i * 8);
    f32x4 v0 = src[0], v1 = src[1];
    u32x4 pk;
    pk[0] = cvt_pk(v0[0], v0[1]); pk[1] = cvt_pk(v0[2], v0[3]);
    pk[2] = cvt_pk(v1[0], v1[1]); pk[3] = cvt_pk(v1[2], v1[3]);
    *(u32x4*)(xb + (size_t)i * 8) = pk;
}

// ---------------- Kernel A: conv1d(k=3,pad=1) + GELU + avgpool(32) + BN ----------------
__global__ __launch_bounds__(256) void krouter_conv(
    const float* __restrict__ x, const float* __restrict__ cw, const float* __restrict__ cb,
    const float* __restrict__ bng, const float* __restrict__ bnb,
    const float* __restrict__ bnm, const float* __restrict__ bnv,
    float* __restrict__ h, int* __restrict__ cnt)
{
    __shared__ float xs[CIN * 264];
    int half = blockIdx.x;
    int b = blockIdx.y;
    int t = threadIdx.x;
    if (b == 0 && half == 0 && t < NE) cnt[t] = 0;

    int Lchunk0 = half * 64 - 1;
    const float* xb_ = x + (size_t)b * DIN;
    for (int idx = t; idx < CIN * 66; idx += 256) {
        int ci = idx / 66;
        int cc = idx - ci * 66;
        int gc = min(max(Lchunk0 + cc, 0), 127);
        f32x4 v = *(const f32x4*)(xb_ + ci * 512 + gc * 4);
        int byte = ci * 1056 + ((cc << 4) ^ (((cc >> 3) & 7) << 4));
        *(f32x4*)((char*)xs + byte) = v;
    }
    __syncthreads();

    int p  = t & 7;
    int pg = half * 8 + p;
    int cq = t >> 3;
    int co0 = cq * 2, co1 = co0 + 1;

    float sa[32], sb[32];
    #pragma unroll
    for (int i = 0; i < 32; ++i) { sa[i] = 0.f; sb[i] = 0.f; }

    for (int ci = 0; ci < CIN; ++ci) {
        float f[40];
        #pragma unroll
        for (int u = 0; u < 10; ++u) {
            int lc = p * 8 + u;
            int byte = ci * 1056 + ((lc << 4) ^ (((lc >> 3) & 7) << 4));
            f32x4 v = *(const f32x4*)((const char*)xs + byte);
            f[4*u+0] = v[0]; f[4*u+1] = v[1]; f[4*u+2] = v[2]; f[4*u+3] = v[3];
        }
        if (pg == 0)  f[3]  = 0.f;
        if (pg == 15) f[36] = 0.f;
        float wa0 = cw[co0*96 + ci*3 + 0], wa1 = cw[co0*96 + ci*3 + 1], wa2 = cw[co0*96 + ci*3 + 2];
        float wb0 = cw[co1*96 + ci*3 + 0], wb1 = cw[co1*96 + ci*3 + 1], wb2 = cw[co1*96 + ci*3 + 2];
        #pragma unroll
        for (int i = 0; i < 32; ++i) {
            sa[i] = fmaf(f[i+3], wa0, fmaf(f[i+4], wa1, fmaf(f[i+5], wa2, sa[i])));
            sb[i] = fmaf(f[i+3], wb0, fmaf(f[i+4], wb1, fmaf(f[i+5], wb2, sb[i])));
        }
    }

    float ba = cb[co0], bbv = cb[co1];
    float ma = 0.f, mb = 0.f;
    #pragma unroll
    for (int i = 0; i < 32; ++i) { ma += gelu_erf(sa[i] + ba); mb += gelu_erf(sb[i] + bbv); }
    ma *= (1.f / 32.f); mb *= (1.f / 32.f);

    int oa = co0 * NPOOL + pg, ob = co1 * NPOOL + pg;
    float ra = (ma - bnm[oa]) * rsqrtf(bnv[oa] + 1e-5f) * bng[oa] + bnb[oa];
    float rb = (mb - bnm[ob]) * rsqrtf(bnv[ob] + 1e-5f) * bng[ob] + bnb[ob];
    h[(size_t)b * HD + oa] = ra;
    h[(size_t)b * HD + ob] = rb;
}

// ---------------- Kernel B: fc1+GELU, fc2, gumbel softmax, top-2, expert row lists ----------
__global__ __launch_bounds__(256) void krouter_fc(
    const float* __restrict__ h, const float* __restrict__ f1w, const float* __restrict__ f1b,
    const float* __restrict__ f2w, const float* __restrict__ f2b,
    const float* __restrict__ gu,
    int* __restrict__ top2e, float* __restrict__ top2w,
    int* __restrict__ cnt, int* __restrict__ rowlist, float* __restrict__ roww)
{
    __shared__ float hs[8 * HD];
    __shared__ float h1s[8 * F1];
    __shared__ float lg[8 * NE];

    int bb = blockIdx.x * 8;
    int t = threadIdx.x;

    const f32x4* hg = (const f32x4*)(h + (size_t)bb * HD);
    f32x4* hs4 = (f32x4*)hs;
    #pragma unroll
    for (int u = 0; u < 8; ++u) hs4[t + 256 * u] = hg[t + 256 * u];
    __syncthreads();

    int j = t & 127;
    int pr = t >> 7;
    float acc[4] = {0.f, 0.f, 0.f, 0.f};
    const f32x4* w4 = (const f32x4*)(f1w + (size_t)j * HD);
    for (int k4 = 0; k4 < 256; ++k4) {
        f32x4 w = w4[k4];
        #pragma unroll
        for (int g = 0; g < 4; ++g) {
            f32x4 hv = hs4[(pr * 4 + g) * 256 + k4];
            acc[g] += w[0]*hv[0] + w[1]*hv[1] + w[2]*hv[2] + w[3]*hv[3];
        }
    }
    float bj = f1b[j];
    #pragma unroll
    for (int g = 0; g < 4; ++g) h1s[(pr * 4 + g) * F1 + j] = gelu_erf(acc[g] + bj);
    __syncthreads();

    if (t < 64) {
        int bi = t >> 3, e = t & 7;
        float s = f2b[e];
        const float* w = f2w + e * F1;
        const float* hh = h1s + bi * F1;
        #pragma unroll 8
        for (int k = 0; k < F1; ++k) s += hh[k] * w[k];
        lg[bi * NE + e] = s;
    }
    __syncthreads();

    if (t < 8) {
        int bi = t; int b = bb + bi;
        float r[NE];
        float mx = -1e30f;
        #pragma unroll
        for (int e = 0; e < NE; ++e) {
            float g = -logf(-logf(gu[b * NE + e]));
            r[e] = lg[bi * NE + e] + g;
            mx = fmaxf(mx, r[e]);
        }
        float sum = 0.f;
        #pragma unroll
        for (int e = 0; e < NE; ++e) { r[e] = expf(r[e] - mx); sum += r[e]; }
        float inv = 1.f / sum;
        #pragma unroll
        for (int e = 0; e < NE; ++e) r[e] *= inv;
        int e0 = 0; float v0 = r[0];
        #pragma unroll
        for (int e = 1; e < NE; ++e) if (r[e] > v0) { v0 = r[e]; e0 = e; }
        int e1 = -1; float v1 = -1.f;
        #pragma unroll
        for (int e = 0; e < NE; ++e) { if (e == e0) continue; if (r[e] > v1) { v1 = r[e]; e1 = e; } }
        float den = v0 + v1 + 1e-8f;
        float w0 = v0 / den, w1 = v1 / den;
        top2e[b * 2 + 0] = e0; top2e[b * 2 + 1] = e1;
        top2w[b * 2 + 0] = w0; top2w[b * 2 + 1] = w1;
        int p0 = atomicAdd(&cnt[e0], 1);
        rowlist[e0 * NB + p0] = b * 2 + 0; roww[e0 * NB + p0] = w0;
        int p1 = atomicAdd(&cnt[e1], 1);
        rowlist[e1 * NB + p1] = b * 2 + 1; roww[e1 * NB + p1] = w1;
    }
}

// ---------------- Kernel C: gathered expert GEMM ----------------------------------------
// MT=256, NT=64, BK=32, 512 thr (8 waves 4m x 2n, wave tile 64x32), LDS 48KB -> 3 blk/CU.
// B (HBM stream) via global_load_lds DMA (1/wave/step), source chunk-XOR pre-swizzled.
// A from pre-converted bf16 xb (L2), reg->LDS, stored AFTER MFMA so latency hides.
// One __syncthreads per step; DMA ages through the whole MFMA phase before the drain.
__global__ __launch_bounds__(512, 2) void kgemm(
    const unsigned short* __restrict__ xb, const float* __restrict__ ew,
    const int* __restrict__ cnt, const int* __restrict__ rowlist, const float* __restrict__ roww,
    unsigned short* __restrict__ ypart, int nkc, int kch)
{
    // bijective XCD-chunk swizzle: 1536 wgs -> 192/XCD = exactly one expert per XCD
    int nwg = gridDim.x;
    int cpx = nwg >> 3;
    int wg = (blockIdx.x & 7) * cpx + (blockIdx.x >> 3);
    int nt = wg % 12;
    int kc = (wg / 12) % nkc;
    int e  = wg / (12 * nkc);
    int cn = cnt[e];

    __shared__ __align__(16) char As[2][MT * BK * 2];   // 2 x 16KB bf16 [m][k-chunk swz]
    __shared__ __align__(16) char Bs[2][BK * NT * 4];   // 2 x 8KB  fp32 [k][n-chunk swz]

    int t = threadIdx.x;
    int wid = t >> 6, lane = t & 63;
    int wm = wid >> 1, wn = wid & 1;
    int g = lane >> 4;
    int NS = kch / BK;
    int k0 = kc * kch;

    // --- B DMA: wave wid stages seg wid (1KB = 4 k-rows x 16 chunks) ---
    const char* gB = (const char*)ew + (size_t)e * DIN * DOUT * 4
                   + (size_t)k0 * (DOUT * 4) + nt * NT * 4;
    int bk_ = wid * 4 + (lane >> 4);            // k-row 0..31
    int bc_ = lane & 15;                        // chunk 0..15
    int bkey = ((bk_ >> 3) & 3) << 2;           // = k-group << 2
    const char* gp = gB + (size_t)bk_ * (DOUT * 4) + ((bc_ ^ bkey) << 4);
    int ldsB = wid * 1024;                      // dest base (+ lane*16 by HW)

    // --- A staging: thread t -> row t>>1 (0..255), half t&1 (16 k = 2 chunks of 16B) ---
    int ar = t >> 1, ah = t & 1;
    int akey_ = (ar >> 1) & 3;
    int ach0 = ((2 * ah) ^ akey_) << 4;
    int ach1 = ((2 * ah + 1) ^ akey_) << 4;

    for (int row0 = 0; row0 < cn; row0 += MT) {
        int mloc = min(MT, cn - row0);
        int arc = min(ar, mloc - 1);
        int ent_a = rowlist[e * NB + row0 + arc];
        const char* axp = (const char*)xb
                        + ((size_t)(ent_a >> 1) * DIN + k0) * 2 + ah * 32;
        bool ado = (ar < mloc);
        bool wact = (wm * 64 < mloc);

        f32x4 acc[4][2];
        #pragma unroll
        for (int i = 0; i < 4; ++i)
            #pragma unroll
            for (int jj = 0; jj < 2; ++jj) acc[i][jj] = (f32x4){0.f, 0.f, 0.f, 0.f};

        u32x4 A0, A1;
        const char* bp = gp;

        auto loadA = [&](int s) {
            if (ado) {
                const u32x4* p = (const u32x4*)(axp + (size_t)s * (BK * 2));
                A0 = p[0]; A1 = p[1];
            }
        };
        auto stageB = [&](int bi) {
            gload_lds16(bp, (char*)Bs[bi] + ldsB);
        };
        auto storeA = [&](int bi) {
            if (ado) {
                *(u32x4*)(As[bi] + ar * 64 + ach0) = A0;
                *(u32x4*)(As[bi] + ar * 64 + ach1) = A1;
            }
        };

        // prologue: tile 0 -> buf 0 (one exposed drain)
        loadA(0);
        stageB(0);
        storeA(0);
        __syncthreads();

        for (int s = 0; s < NS; ++s) {
            int buf = s & 1;
            if (s + 1 < NS) {
                loadA(s + 1);                  // A loads oldest in vmcnt queue
                bp += (size_t)BK * DOUT * 4;
                stageB(buf ^ 1);               // DMA newest; stays in flight
            }

            if (wact) {
                const char* Ab = As[buf];
                const char* Bb = Bs[buf];
                s16x8 af[4];
                #pragma unroll
                for (int mi = 0; mi < 4; ++mi) {
                    int m = wm * 64 + mi * 16 + (lane & 15);
                    af[mi] = *(const s16x8*)(Ab + m * 64 + ((g ^ ((m >> 1) & 3)) << 4));
                }
                #pragma unroll
                for (int ni = 0; ni < 2; ++ni) {
                    int n = wn * 32 + ni * 16 + (lane & 15);
                    int cb = (((n >> 2) ^ (g << 2)) << 4) + ((n & 3) << 2);
                    float v[8];
                    #pragma unroll
                    for (int j = 0; j < 8; ++j)
                        v[j] = *(const float*)(Bb + (g * 8 + j) * 256 + cb);
                    union { u32x4 u; s16x8 s; } bf;
                    bf.u[0] = cvt_pk(v[0], v[1]); bf.u[1] = cvt_pk(v[2], v[3]);
                    bf.u[2] = cvt_pk(v[4], v[5]); bf.u[3] = cvt_pk(v[6], v[7]);
                    #pragma unroll
                    for (int mi = 0; mi < 4; ++mi)
                        acc[mi][ni] = __builtin_amdgcn_mfma_f32_16x16x32_bf16(af[mi], bf.s, acc[mi][ni], 0, 0, 0);
                }
            }

            __builtin_amdgcn_sched_barrier(0);   // keep storeA (and its vmcnt) after MFMA
            if (s + 1 < NS) storeA(buf ^ 1);     // waits A loads only; DMA still in flight
            __syncthreads();                      // drains DMA, aged a full MFMA phase
        }

        // ---- epilogue: gate weight, bf16 scatter to per-(slot,kc) partial plane ----
        if (wact) {
            #pragma unroll
            for (int mi = 0; mi < 4; ++mi) {
                #pragma unroll
                for (int rg = 0; rg < 4; ++rg) {
                    int m = wm * 64 + mi * 16 + g * 4 + rg;
                    if (m < mloc) {
                        int ent = rowlist[e * NB + row0 + m];
                        float wgt = roww[e * NB + row0 + m];
                        int ob = ent >> 1, slot = ent & 1;
                        unsigned short* dst = ypart + ((size_t)(slot * nkc + kc) * NB + ob) * DOUT
                                            + nt * NT + wn * 32 + (lane & 15);
                        #pragma unroll
                        for (int ni = 0; ni < 2; ++ni)
                            dst[ni * 16] = f2bf_u(acc[mi][ni][rg] * wgt);
                    }
                }
            }
        }
        __syncthreads();
    }
}

// ---------------- Kernel D: combine bf16 partial planes + weighted expert bias ------------
__global__ __launch_bounds__(256) void kcombine(
    const unsigned short* __restrict__ ypart,
    const int* __restrict__ top2e, const float* __restrict__ top2w,
    const float* __restrict__ eb, float* __restrict__ out, int nplanes)
{
    int b = blockIdx.y;
    int n = blockIdx.x * 256 + threadIdx.x;
    float s = 0.f;
    for (int p = 0; p < nplanes; ++p) {
        unsigned v = ypart[((size_t)p * NB + b) * DOUT + n];
        union { unsigned u; float f; } c; c.u = v << 16;
        s += c.f;
    }
    int e0 = top2e[b * 2], e1 = top2e[b * 2 + 1];
    float w0 = top2w[b * 2], w1 = top2w[b * 2 + 1];
    s += w0 * eb[e0 * DOUT + n] + w1 * eb[e1 * DOUT + n];
    out[(size_t)b * DOUT + n] = s;
}

extern "C" void kernel_launch(void* const* d_in, const int* in_sizes, int n_in,
                              void* d_out, int out_size, void* d_ws, size_t ws_size,
                              hipStream_t stream)
{
    const float* x   = (const float*)d_in[0];
    const float* gu  = (const float*)d_in[1];
    const float* cw  = (const float*)d_in[2];
    const float* cb  = (const float*)d_in[3];
    const float* bng = (const float*)d_in[4];
    const float* bnb = (const float*)d_in[5];
    const float* bnm = (const float*)d_in[6];
    const float* bnv = (const float*)d_in[7];
    const float* f1w = (const float*)d_in[8];
    const float* f1b = (const float*)d_in[9];
    const float* f2w = (const float*)d_in[10];
    const float* f2b = (const float*)d_in[11];
    const float* ew  = (const float*)d_in[12];
    const float* eb  = (const float*)d_in[13];

    int nkc = (ws_size >= (size_t)64 * 1024 * 1024) ? 16 : 8;
    int kch = DIN / nkc;

    char* ws = (char*)d_ws;
    size_t off = 0;
    float* h       = (float*)(ws + off); off += (size_t)NB * HD * 4;
    int*   top2e   = (int*)(ws + off);   off += (size_t)NB * 2 * 4;
    float* top2w   = (float*)(ws + off); off += (size_t)NB * 2 * 4;
    int*   cnt     = (int*)(ws + off);   off += 256;
    int*   rowlist = (int*)(ws + off);   off += (size_t)NE * NB * 4;
    float* roww    = (float*)(ws + off); off += (size_t)NE * NB * 4;
    unsigned short* xbuf = (unsigned short*)(ws + off);
    off += (size_t)NB * DIN * 2;                               // 16 MB bf16 x
    unsigned short* ypart = (unsigned short*)(ws + off);
    off += (size_t)2 * nkc * NB * DOUT * 2;

    kcvt<<<(NB * DIN / 8 + 255) / 256, 256, 0, stream>>>(x, xbuf);
    krouter_conv<<<dim3(2, NB), 256, 0, stream>>>(x, cw, cb, bng, bnb, bnm, bnv, h, cnt);
    krouter_fc<<<NB / 8, 256, 0, stream>>>(h, f1w, f1b, f2w, f2b, gu,
                                           top2e, top2w, cnt, rowlist, roww);
    kgemm<<<NE * nkc * 12, 512, 0, stream>>>(xbuf, ew, cnt, rowlist, roww, ypart, nkc, kch);
    kcombine<<<dim3(3, NB), 256, 0, stream>>>(ypart, top2e, top2w, eb, (float*)d_out, 2 * nkc);
}